// Round 11
// baseline (104.721 us; speedup 1.0000x reference)
//
#include <hip/hip_runtime.h>

// Problem constants
#define BATCH 4
#define SEQ   2048
#define INC   512
#define NH    8
#define OUTC  64      // space dim; head dim = 65
#define DD    65
#define NROW  (BATCH * NH * SEQ)   // 65536

typedef float f32x4 __attribute__((ext_vector_type(4)));
typedef short short8 __attribute__((ext_vector_type(8)));
typedef short short4v __attribute__((ext_vector_type(4)));
typedef unsigned short us;

static __device__ __forceinline__ us f2b(float f) {
  unsigned int u = __float_as_uint(f);
  u = (u + 0x7FFFu + ((u >> 16) & 1u)) >> 16;   // RNE f32->bf16
  return (us)u;
}
static __device__ __forceinline__ float b2f(us h) {
  return __uint_as_float(((unsigned int)h) << 16);
}
static __device__ __forceinline__ unsigned int pk2(float lo, float hi) {
  unsigned int r;
  asm("v_cvt_pk_bf16_f32 %0, %1, %2" : "=v"(r) : "v"(lo), "v"(hi));
  return r;
}

#define GLDS(g, l) __builtin_amdgcn_global_load_lds( \
    (const __attribute__((address_space(1))) void*)(g), \
    (__attribute__((address_space(3))) void*)(l), 16, 0, 0)
#define SB() __builtin_amdgcn_sched_barrier(0)

// ---------------------------------------------------------------------------
// Kernel 0: f32 -> bf16 conversion for X (both) and W (all three).
// ---------------------------------------------------------------------------
__global__ __launch_bounds__(256) void tobf16_kernel(
    const float* __restrict__ Xq, const float* __restrict__ Xs,
    const float* __restrict__ Wq, const float* __restrict__ Wk,
    const float* __restrict__ Wv,
    us* __restrict__ dXq, us* __restrict__ dXs,
    us* __restrict__ dWq, us* __restrict__ dWk, us* __restrict__ dWv)
{
  const int which = blockIdx.y;
  const float* src;
  us* dst;
  int n;
  switch (which) {
    case 0: src = Xq; dst = dXq; n = BATCH * SEQ * INC; break;
    case 1: src = Xs; dst = dXs; n = BATCH * SEQ * INC; break;
    case 2: src = Wq; dst = dWq; n = NH * OUTC * INC; break;
    case 3: src = Wk; dst = dWk; n = NH * OUTC * INC; break;
    default: src = Wv; dst = dWv; n = NH * OUTC * INC; break;
  }
  for (long i = (long)blockIdx.x * 256 + threadIdx.x; i * 4 < n;
       i += (long)gridDim.x * 256) {
    f32x4 v = *(const f32x4*)(src + i * 4);
    short4v o;
    o[0] = (short)f2b(v[0]); o[1] = (short)f2b(v[1]);
    o[2] = (short)f2b(v[2]); o[3] = (short)f2b(v[3]);
    *(short4v*)(dst + i * 4) = o;
  }
}

// ---------------------------------------------------------------------------
// Kernel 1: per-head projections, GLDS double-buffered (unchanged, passed).
// ---------------------------------------------------------------------------
__global__ __launch_bounds__(256) void proj_kernel(
    const us* __restrict__ Xqb, const us* __restrict__ Xsb,
    const us* __restrict__ Wqb, const us* __restrict__ Wkb, const us* __restrict__ Wvb,
    const float* __restrict__ Bq, const float* __restrict__ Bk, const float* __restrict__ Bv,
    const float* __restrict__ scale_p,
    us* __restrict__ qs, unsigned int* __restrict__ qta,
    us* __restrict__ ks, unsigned int* __restrict__ kta,
    us* __restrict__ vs, us* __restrict__ vtc)
{
  const int which = blockIdx.z;
  const us* X = (which == 0) ? Xqb : Xsb;
  const us* W = (which == 0) ? Wqb : (which == 1 ? Wkb : Wvb);
  const float* Bb = (which == 0) ? Bq : (which == 1 ? Bk : Bv);
  us* outs = (which == 0) ? qs : (which == 1 ? ks : vs);
  const float al2 = (2.0f / scale_p[0]) * 1.44269504088896f;
  const float oscale = (which == 0) ? al2 : 1.0f;

  const int lin = blockIdx.x;                    // 0..1023
  const int h   = (lin >> 3) & 7;
  const int m0  = (((lin >> 6) << 3) | (lin & 7)) * 64;
  const int n0  = h * 64;

  __shared__ alignas(16) us lX[2][64 * 64];
  __shared__ alignas(16) us lW[2][64 * 64];

  const int tid  = threadIdx.x;
  const int lane = tid & 63;
  const int wave = tid >> 6;
  const int arow = lane & 15;
  const int agrp = lane >> 4;
  const int rl   = lane >> 3;
  const int chx  = ((lane & 7) ^ rl) * 8;
  const int r0   = wave * 8 + rl;
  const int r1   = r0 + 32;

#define PSTAGE(buf, k0) do { \
    GLDS(X + (size_t)(m0 + r0) * INC + (k0) + chx, &lX[buf][wave * 512]); \
    GLDS(X + (size_t)(m0 + r1) * INC + (k0) + chx, &lX[buf][2048 + wave * 512]); \
    GLDS(W + (size_t)(n0 + r0) * INC + (k0) + chx, &lW[buf][wave * 512]); \
    GLDS(W + (size_t)(n0 + r1) * INC + (k0) + chx, &lW[buf][2048 + wave * 512]); \
  } while (0)

  f32x4 acc[4] = {};
  PSTAGE(0, 0);

  for (int kk = 0; kk < 8; ++kk) {
    const int cur = kk & 1;
    if (kk < 7) {
      PSTAGE(cur ^ 1, (kk + 1) * 64);
      asm volatile("s_waitcnt vmcnt(4)");
    } else {
      asm volatile("s_waitcnt vmcnt(0)");
    }
    __builtin_amdgcn_s_barrier();
#pragma unroll
    for (int kc = 0; kc < 2; ++kc) {
      short8 af = *(const short8*)&lX[cur][(wave * 16 + arow) * 64 + (((kc * 4 + agrp) ^ (arow & 7)) * 8)];
#pragma unroll
      for (int c = 0; c < 4; ++c) {
        short8 bf = *(const short8*)&lW[cur][(c * 16 + arow) * 64 + (((kc * 4 + agrp) ^ (arow & 7)) * 8)];
        acc[c] = __builtin_amdgcn_mfma_f32_16x16x32_bf16(af, bf, acc[c], 0, 0, 0);
      }
    }
    __builtin_amdgcn_s_barrier();
  }

  float bcol[4];
#pragma unroll
  for (int c = 0; c < 4; ++c) bcol[c] = Bb[n0 + c * 16 + arow];
#pragma unroll
  for (int r = 0; r < 4; ++r) {
    float s2 = 0.f;
#pragma unroll
    for (int c = 0; c < 4; ++c) {
      float v = acc[c][r] + bcol[c];
      acc[c][r] = v;
      s2 += v * v;
    }
    s2 += __shfl_xor(s2, 1); s2 += __shfl_xor(s2, 2);
    s2 += __shfl_xor(s2, 4); s2 += __shfl_xor(s2, 8);
    float tv = sqrtf(s2 + 1.0f);
    int gs = m0 + wave * 16 + agrp * 4 + r;
    int bi = gs >> 11, si = gs & (SEQ - 1);
    size_t rowbase = (size_t)(bi * NH + h) * SEQ + si;
    size_t obase = rowbase * 64;
#pragma unroll
    for (int c = 0; c < 4; ++c) outs[obase + c * 16 + arow] = f2b(oscale * acc[c][r]);
    if (arow == 0) {
      if (which == 0) {
        float st = al2 * tv;
        us qh = f2b(st);
        us ql = f2b(st - b2f(qh));
        qta[rowbase] = (unsigned int)qh | ((unsigned int)ql << 16);
      } else {
        us th = f2b(tv);
        us tl = f2b(tv - b2f(th));
        if (which == 1) {
          kta[rowbase] = (unsigned int)(us)(th ^ 0x8000)
                       | ((unsigned int)(us)(tl ^ 0x8000) << 16);
        } else {
          vtc[rowbase] = th;
          vtc[NROW + rowbase] = tl;
        }
      }
    }
  }
}

// ---------------------------------------------------------------------------
// Kernel 2: PLAIN transpose of V space-part per (b,h): [S,64] -> [64,S].
// (R7 version — the k-permutation for in-reg P is reverted.)
// ---------------------------------------------------------------------------
__global__ __launch_bounds__(256) void transpose_v_kernel(
    const us* __restrict__ vs, us* __restrict__ vT)
{
  const int bh = blockIdx.y;
  const int s0 = blockIdx.x * 64;
  __shared__ us lT[64 * 80];
  const int tid = threadIdx.x;
#pragma unroll
  for (int u0 = 0; u0 < 2; ++u0) {
    int u = tid + u0 * 256;
    int row = u >> 3, ch = u & 7;
    short8 v = *(const short8*)&vs[((size_t)bh * SEQ + s0 + row) * 64 + ch * 8];
    *(short8*)&lT[row * 80 + ch * 8] = v;
  }
  __syncthreads();
#pragma unroll
  for (int u0 = 0; u0 < 2; ++u0) {
    int u = tid + u0 * 256;
    int o = u >> 3, sc = u & 7;
    short8 w;
#pragma unroll
    for (int j = 0; j < 8; ++j) w[j] = lT[(sc * 8 + j) * 80 + o];
    *(short8*)&vT[((size_t)bh * 64 + o) * SEQ + s0 + sc * 8] = w;
  }
}

// ---------------------------------------------------------------------------
// Kernel 3: 2-way split-k causal flash attention with WAVE ROLE SPLIT:
// 4 waves = (qh in {0,1}) x (kh in {0,1}). Each wave: 32 q-rows x its 32-k
// half -> K/V/P LDS reads HALVE vs R7 (the measured bottleneck: R7 ran at
// ~51 TB/s LDS ~ 73% of ceiling). kh-partials merged once per segment via
// LDS (lK reused after final barrier); kh=1 waves write the partial.
// vmcnt queue (aug = 2 kt + 1 vt = 3): it==0 -> 4; steady -> 7; last -> 3;
// nt==1 -> 0.
// ---------------------------------------------------------------------------
__global__ __launch_bounds__(256) void attn_kernel(
    const us* __restrict__ qs, const unsigned int* __restrict__ qta,
    const us* __restrict__ ks, const unsigned int* __restrict__ kta,
    const us* __restrict__ vT, const us* __restrict__ vtc,
    float* __restrict__ part)
{
  // XCD-aware swizzle: 32 blocks of one bh land on one XCD.
  const int f = blockIdx.x;
  const int xcd = f & 7, idx = f >> 3;
  const int bh = xcd * 4 + (idx >> 5);
  const int inner = idx & 31;
  const int xb = inner >> 1;
  const int hf = inner & 1;

  __shared__ alignas(16) us lK[2][64 * 64];
  __shared__ alignas(16) us lV[2][64 * 64];
  __shared__ alignas(16) us lP[4][32 * 40];   // per-wave 32 q-rows x 80B

  const int tid  = threadIdx.x;
  const int lane = tid & 63;
  const int wave = tid >> 6;
  const int arow = lane & 15;
  const int agrp = lane >> 4;
  const int qh   = wave >> 1;    // q-half role
  const int kh   = wave & 1;     // k-half role

  const size_t bhbase = (size_t)bh * SEQ;
  const us* kgp = ks + bhbase * 64;
  const us* vgp = vT + (size_t)bh * 64 * SEQ;
  const unsigned int* ktp = kta + bhbase;
  const us* vtp = vtc + (size_t)(arow & 1) * NROW + bhbase;

  const int rl   = lane >> 3;
  const int chx  = ((lane & 7) ^ rl) * 8;
  const int r0s  = wave * 8 + rl;
  const int r1s  = r0s + 32;
  const int dsl0 = (agrp ^ (arow & 7)) * 8;              // K read, d-half 0
  const int dsl1 = ((4 + agrp) ^ (arow & 7)) * 8;        // K read, d-half 1
  const int dslK = (((kh << 2) + agrp) ^ (arow & 7)) * 8; // V read, my k-half
  us* myP = &lP[wave][0];
  const int pw0 = arow * 40 + agrp * 4;   // P b64 write (c=1: +16; qset: +640)
  const int prd = arow * 40 + agrp * 8;   // pf b128 read

#define ASTAGE(buf, t64) do { \
    const int kk = (t64) * 64; \
    GLDS(kgp + (size_t)(kk + r0s) * 64 + chx, &lK[buf][wave * 512]); \
    GLDS(kgp + (size_t)(kk + r1s) * 64 + chx, &lK[buf][2048 + wave * 512]); \
    GLDS(vgp + (size_t)r0s * SEQ + kk + chx, &lV[buf][wave * 512]); \
    GLDS(vgp + (size_t)r1s * SEQ + kk + chx, &lV[buf][2048 + wave * 512]); \
  } while (0)

  short8 ones8, zero8 = {};
#pragma unroll
  for (int j = 0; j < 8; ++j) ones8[j] = (short)0x3F80;

  for (int seg = 0; seg < 2; ++seg) {
    const int qb = seg ? (31 - xb) : xb;
    const int q0 = qb * 64;
    const int c0 = (qb + 2) >> 1;           // ceil((qb+1)/2)
    const int t_lo = hf ? c0 : 0;
    const int t_hi = hf ? (qb + 1) : c0;
    const int nt = t_hi - t_lo;

    f32x4 acc[2][4] = {};   // [qset][dc]: rows q=qset*16+agrp*4+r, col d=dc*16+arow
    f32x4 ac4[2] = {};      // aug: cols {t_hi, t_lo, lsum} at arow 0/1/2

    if (nt > 0) {
      // Q for both qsets (6 VMEM)
      int wq0 = q0 + qh * 32 + arow;
      int wq1 = wq0 + 16;
      const us* qp0 = qs + (bhbase + wq0) * 64;
      const us* qp1 = qs + (bhbase + wq1) * 64;
      short8 qf0a = *(const short8*)(qp0 + agrp * 8);
      short8 qf1a = *(const short8*)(qp0 + 32 + agrp * 8);
      short8 qf0b = *(const short8*)(qp1 + agrp * 8);
      short8 qf1b = *(const short8*)(qp1 + 32 + agrp * 8);
      unsigned int qwa = qta[bhbase + wq0];
      unsigned int qwb = qta[bhbase + wq1];
      short8 qf2a = {}, qf2b = {};
      if (agrp == 0) {
        qf2a[0] = (short)(qwa & 0xFFFFu); qf2a[1] = (short)(qwa & 0xFFFFu);
        qf2a[2] = (short)(qwa >> 16);
        qf2b[0] = (short)(qwb & 0xFFFFu); qf2b[1] = (short)(qwb & 0xFFFFu);
        qf2b[2] = (short)(qwb >> 16);
      }

      // aug regs for first tile: my k-half only (2 + 1 = 3 VMEM)
      unsigned int ka0, ka1;
      short8 va;
      {
        const int kk = t_lo * 64 + kh * 32;
        ka0 = ktp[kk + arow];
        ka1 = ktp[kk + 16 + arow];
        va = *(const short8*)(vtp + kk + agrp * 8);
      }
      SB();
      ASTAGE(0, t_lo);
      SB();

      for (int it = 0; it < nt; ++it) {
        const int t = t_lo + it;
        const int cur = it & 1;
        if (it < nt - 1) {
          ASTAGE(cur ^ 1, t + 1);
          SB();
          if (it == 0) asm volatile("s_waitcnt vmcnt(4)");
          else         asm volatile("s_waitcnt vmcnt(7)");
        } else {
          SB();
          if (nt > 1) asm volatile("s_waitcnt vmcnt(3)");
          else        asm volatile("s_waitcnt vmcnt(0)");
        }
        SB();
        __builtin_amdgcn_s_barrier();

        const us* Kb = lK[cur];
        const us* Vb = lV[cur];

        // ---- S^T = K' Q'^T on my (k-half x 32 q): lane: q=arow(+qset*16),
        //      k = kh*32 + c*16 + agrp*4 + r ----
        f32x4 sa[2] = {}, sb[2] = {};   // [c] for qset a/b
        __builtin_amdgcn_s_setprio(1);
#pragma unroll
        for (int c = 0; c < 2; ++c) {
          short8 kf = *(const short8*)&Kb[(kh * 32 + c * 16 + arow) * 64 + dsl0];
          sa[c] = __builtin_amdgcn_mfma_f32_16x16x32_bf16(kf, qf0a, sa[c], 0, 0, 0);
          sb[c] = __builtin_amdgcn_mfma_f32_16x16x32_bf16(kf, qf0b, sb[c], 0, 0, 0);
        }
#pragma unroll
        for (int c = 0; c < 2; ++c) {
          short8 kf = *(const short8*)&Kb[(kh * 32 + c * 16 + arow) * 64 + dsl1];
          sa[c] = __builtin_amdgcn_mfma_f32_16x16x32_bf16(kf, qf1a, sa[c], 0, 0, 0);
          sb[c] = __builtin_amdgcn_mfma_f32_16x16x32_bf16(kf, qf1b, sb[c], 0, 0, 0);
        }
#pragma unroll
        for (int c = 0; c < 2; ++c) {
          short8 kf2 = {};
          if (agrp == 0) {
            unsigned int w0 = c ? ka1 : ka0;
            kf2[0] = (short)(w0 & 0xFFFFu);
            kf2[1] = (short)(w0 >> 16);
            kf2[2] = (short)(w0 & 0xFFFFu);
          }
          sa[c] = __builtin_amdgcn_mfma_f32_16x16x32_bf16(kf2, qf2a, sa[c], 0, 0, 0);
          sb[c] = __builtin_amdgcn_mfma_f32_16x16x32_bf16(kf2, qf2b, sb[c], 0, 0, 0);
        }
        __builtin_amdgcn_s_setprio(0);

        // ---- P = exp2(logit); causal mask -> exact 0 ----
#pragma unroll
        for (int c = 0; c < 2; ++c)
#pragma unroll
          for (int r = 0; r < 4; ++r) {
            sa[c][r] = exp2f(sa[c][r]);
            sb[c][r] = exp2f(sb[c][r]);
          }
        if (t == qb) {
          const int kb = t * 64 + kh * 32;
#pragma unroll
          for (int c = 0; c < 2; ++c)
#pragma unroll
            for (int r = 0; r < 4; ++r) {
              int k = kb + c * 16 + agrp * 4 + r;
              if (k > q0 + qh * 32 + arow)      sa[c][r] = 0.f;
              if (k > q0 + qh * 32 + 16 + arow) sb[c][r] = 0.f;
            }
        }

        // ---- P -> LDS (4 b64), then PV on my k-half (K=32, 1 MFMA pass) ----
        {
          typedef unsigned int uint2v __attribute__((ext_vector_type(2)));
          uint2v w;
          w[0] = pk2(sa[0][0], sa[0][1]); w[1] = pk2(sa[0][2], sa[0][3]);
          *(uint2v*)&myP[pw0] = w;
          w[0] = pk2(sa[1][0], sa[1][1]); w[1] = pk2(sa[1][2], sa[1][3]);
          *(uint2v*)&myP[pw0 + 16] = w;
          w[0] = pk2(sb[0][0], sb[0][1]); w[1] = pk2(sb[0][2], sb[0][3]);
          *(uint2v*)&myP[640 + pw0] = w;
          w[0] = pk2(sb[1][0], sb[1][1]); w[1] = pk2(sb[1][2], sb[1][3]);
          *(uint2v*)&myP[640 + pw0 + 16] = w;
        }
        __builtin_amdgcn_s_setprio(1);
        {
          short8 pfa = *(const short8*)&myP[prd];
          short8 pfb = *(const short8*)&myP[640 + prd];
#pragma unroll
          for (int dc = 0; dc < 4; ++dc) {
            short8 vf = *(const short8*)&Vb[(dc * 16 + arow) * 64 + dslK];
            acc[0][dc] = __builtin_amdgcn_mfma_f32_16x16x32_bf16(pfa, vf, acc[0][dc], 0, 0, 0);
            acc[1][dc] = __builtin_amdgcn_mfma_f32_16x16x32_bf16(pfb, vf, acc[1][dc], 0, 0, 0);
          }
          short8 vf4 = (arow < 2) ? va : ((arow == 2) ? ones8 : zero8);
          ac4[0] = __builtin_amdgcn_mfma_f32_16x16x32_bf16(pfa, vf4, ac4[0], 0, 0, 0);
          ac4[1] = __builtin_amdgcn_mfma_f32_16x16x32_bf16(pfb, vf4, ac4[1], 0, 0, 0);
        }
        __builtin_amdgcn_s_setprio(0);

        // aug prefetch for next tile (in flight across the barrier)
        SB();
        if (it + 1 < nt) {
          const int kk = (t + 1) * 64 + kh * 32;
          ka0 = ktp[kk + arow];
          ka1 = ktp[kk + 16 + arow];
          va = *(const short8*)(vtp + kk + agrp * 8);
        }
        SB();
        __builtin_amdgcn_s_barrier();   // reads done: safe to overwrite other buf
      }
    }

    // ---- kh-merge via LDS (lK free after final barrier), then write ----
    __syncthreads();
    {
      float* mq = (float*)&lK[0][0] + (size_t)qh * 2048;   // 32q x 64d f32
      float* ma = (float*)&lP[0][0] + (size_t)qh * 128;    // 32q x 4 f32
      if (kh == 0) {
#pragma unroll
        for (int qset = 0; qset < 2; ++qset)
#pragma unroll
          for (int r = 0; r < 4; ++r) {
            int ql = qset * 16 + agrp * 4 + r;
#pragma unroll
            for (int dc = 0; dc < 4; ++dc)
              mq[ql * 64 + dc * 16 + arow] = acc[qset][dc][r];
            if (arow < 3) ma[ql * 4 + arow] = ac4[qset][r];
          }
      }
      __syncthreads();
      if (kh == 1) {
        const size_t pb = ((size_t)(bh * 32 + qb) * 2 + hf) * 64;
#pragma unroll
        for (int qset = 0; qset < 2; ++qset)
#pragma unroll
          for (int r = 0; r < 4; ++r) {
            int ql = qset * 16 + agrp * 4 + r;
            float av = ac4[qset][r] + ((arow < 3) ? ma[ql * 4 + arow] : 0.f);
            float t0 = __shfl(av, (agrp << 4) | 0);
            float t1 = __shfl(av, (agrp << 4) | 1);
            float ls = __shfl(av, (agrp << 4) | 2);
            size_t rp = (pb + qh * 32 + ql) * 68;
#pragma unroll
            for (int dc = 0; dc < 4; ++dc)
              part[rp + dc * 16 + arow] =
                  acc[qset][dc][r] + mq[ql * 64 + dc * 16 + arow];
            if (arow == 0) {
              part[rp + 64] = t0 + t1;
              part[rp + 65] = ls;
            }
          }
      }
      __syncthreads();   // before next segment's ASTAGE reuses lK
    }
  }
}

// ---------------------------------------------------------------------------
// Kernel 4: merge split-k partials (exact sums, m == 0), mean over heads,
// Lorentz normalization. One wave per (b,s); lane = space dim d.
// ---------------------------------------------------------------------------
__global__ __launch_bounds__(256) void finalize_kernel(
    const float* __restrict__ part, float* __restrict__ out)
{
  const int tid  = threadIdx.x;
  const int lane = tid & 63;
  const int gw = blockIdx.x * 4 + (tid >> 6);
  const int b = gw >> 11, si = gw & (SEQ - 1);
  const int qb = si >> 6, row = si & 63;

  float vsum = 0.f, tsum = 0.f;
#pragma unroll
  for (int h = 0; h < NH; ++h) {
    float Ah = 0.f, Th = 0.f, Lh = 0.f;
#pragma unroll
    for (int hf = 0; hf < 2; ++hf) {
      size_t rb = (((size_t)((b * NH + h) * 32 + qb) * 2 + hf) * 64 + row) * 68;
      Ah += part[rb + lane];
      Th += part[rb + 64];
      Lh += part[rb + 65];
    }
    float inv = 1.0f / Lh;
    vsum = fmaf(Ah, inv, vsum);
    tsum = fmaf(Th, inv, tsum);
  }
  float ave  = vsum * 0.125f;
  float tave = tsum * 0.125f;
  float contrib = ave * ave;
  if (lane == 0) contrib -= tave * tave;
  contrib += __shfl_xor(contrib, 1);
  contrib += __shfl_xor(contrib, 2);
  contrib += __shfl_xor(contrib, 4);
  contrib += __shfl_xor(contrib, 8);
  contrib += __shfl_xor(contrib, 16);
  contrib += __shfl_xor(contrib, 32);
  float denom = sqrtf(fmaxf(fabsf(contrib), 1e-8f));
  size_t ob = ((size_t)b * SEQ + si) * (size_t)DD;
  out[ob + 1 + lane] = ave / denom;
  if (lane == 0) out[ob] = tave / denom;
}

// ---------------------------------------------------------------------------
extern "C" void kernel_launch(void* const* d_in, const int* in_sizes, int n_in,
                              void* d_out, int out_size, void* d_ws, size_t ws_size,
                              hipStream_t stream) {
  const float* Xq  = (const float*)d_in[0];
  const float* Xs  = (const float*)d_in[1];
  const float* Wq  = (const float*)d_in[2];
  const float* Bq  = (const float*)d_in[3];
  const float* Wk  = (const float*)d_in[4];
  const float* Bk  = (const float*)d_in[5];
  const float* Wv  = (const float*)d_in[6];
  const float* Bv  = (const float*)d_in[7];
  const float* scale = (const float*)d_in[8];
  float* out = (float*)d_out;

  char* p = (char*)d_ws;

  // Region 0 (35.7 MB): partials, overlapped with bf16 X and W copies
  // (proj consumes Xb/Wb before attn writes part).
  float* part = (float*)p;
  us* Xqb   = (us*)p;
  us* Xsb   = (us*)(p + 16777216);
  us* Wqb16 = (us*)(p + 33554432);
  us* Wkb16 = (us*)(p + 34078720);
  us* Wvb16 = (us*)(p + 34603008);
  p += (size_t)1024 * 2 * 64 * 68 * 4;             // 35,651,584
  us* qsb = (us*)p; p += (size_t)NROW * 64 * 2;
  us* ksb = (us*)p; p += (size_t)NROW * 64 * 2;
  us* vsb = (us*)p; p += (size_t)NROW * 64 * 2;
  us* vTb = (us*)p; p += (size_t)NROW * 64 * 2;
  unsigned int* qtaw = (unsigned int*)p; p += (size_t)NROW * 4;
  unsigned int* ktaw = (unsigned int*)p; p += (size_t)NROW * 4;
  us* vtcw = (us*)p; p += (size_t)NROW * 2 * 2;

  tobf16_kernel<<<dim3(1024, 5), 256, 0, stream>>>(
      Xq, Xs, Wq, Wk, Wv, Xqb, Xsb, Wqb16, Wkb16, Wvb16);
  proj_kernel<<<dim3(1024, 1, 3), 256, 0, stream>>>(
      Xqb, Xsb, Wqb16, Wkb16, Wvb16, Bq, Bk, Bv, scale,
      qsb, qtaw, ksb, ktaw, vsb, vtcw);
  transpose_v_kernel<<<dim3(SEQ / 64, BATCH * NH), 256, 0, stream>>>(vsb, vTb);
  attn_kernel<<<dim3(1024), 256, 0, stream>>>(
      qsb, qtaw, ksb, ktaw, vTb, vtcw, part);
  finalize_kernel<<<(BATCH * SEQ) / 4, 256, 0, stream>>>(part, out);
}

// Round 12
// 100.438 us; speedup vs baseline: 1.0426x; 1.0426x over previous
//
#include <hip/hip_runtime.h>

// Problem constants
#define BATCH 4
#define SEQ   2048
#define INC   512
#define NH    8
#define OUTC  64      // space dim; head dim = 65
#define DD    65
#define NROW  (BATCH * NH * SEQ)   // 65536

typedef float f32x4 __attribute__((ext_vector_type(4)));
typedef short short8 __attribute__((ext_vector_type(8)));
typedef short short4v __attribute__((ext_vector_type(4)));
typedef unsigned int uint2v __attribute__((ext_vector_type(2)));
typedef unsigned short us;

static __device__ __forceinline__ us f2b(float f) {
  unsigned int u = __float_as_uint(f);
  u = (u + 0x7FFFu + ((u >> 16) & 1u)) >> 16;   // RNE f32->bf16
  return (us)u;
}
static __device__ __forceinline__ float b2f(us h) {
  return __uint_as_float(((unsigned int)h) << 16);
}
static __device__ __forceinline__ unsigned int pk2(float lo, float hi) {
  unsigned int r;
  asm("v_cvt_pk_bf16_f32 %0, %1, %2" : "=v"(r) : "v"(lo), "v"(hi));
  return r;
}

#define GLDS(g, l) __builtin_amdgcn_global_load_lds( \
    (const __attribute__((address_space(1))) void*)(g), \
    (__attribute__((address_space(3))) void*)(l), 16, 0, 0)
#define SB() __builtin_amdgcn_sched_barrier(0)

// ---------------------------------------------------------------------------
// Kernel 0: f32 -> bf16 conversion for X (both) and W (all three).
// ---------------------------------------------------------------------------
__global__ __launch_bounds__(256) void tobf16_kernel(
    const float* __restrict__ Xq, const float* __restrict__ Xs,
    const float* __restrict__ Wq, const float* __restrict__ Wk,
    const float* __restrict__ Wv,
    us* __restrict__ dXq, us* __restrict__ dXs,
    us* __restrict__ dWq, us* __restrict__ dWk, us* __restrict__ dWv)
{
  const int which = blockIdx.y;
  const float* src;
  us* dst;
  int n;
  switch (which) {
    case 0: src = Xq; dst = dXq; n = BATCH * SEQ * INC; break;
    case 1: src = Xs; dst = dXs; n = BATCH * SEQ * INC; break;
    case 2: src = Wq; dst = dWq; n = NH * OUTC * INC; break;
    case 3: src = Wk; dst = dWk; n = NH * OUTC * INC; break;
    default: src = Wv; dst = dWv; n = NH * OUTC * INC; break;
  }
  for (long i = (long)blockIdx.x * 256 + threadIdx.x; i * 4 < n;
       i += (long)gridDim.x * 256) {
    f32x4 v = *(const f32x4*)(src + i * 4);
    short4v o;
    o[0] = (short)f2b(v[0]); o[1] = (short)f2b(v[1]);
    o[2] = (short)f2b(v[2]); o[3] = (short)f2b(v[3]);
    *(short4v*)(dst + i * 4) = o;
  }
}

// ---------------------------------------------------------------------------
// Kernel 1: per-head projections, GLDS double-buffered (unchanged, passed).
// ---------------------------------------------------------------------------
__global__ __launch_bounds__(256) void proj_kernel(
    const us* __restrict__ Xqb, const us* __restrict__ Xsb,
    const us* __restrict__ Wqb, const us* __restrict__ Wkb, const us* __restrict__ Wvb,
    const float* __restrict__ Bq, const float* __restrict__ Bk, const float* __restrict__ Bv,
    const float* __restrict__ scale_p,
    us* __restrict__ qs, unsigned int* __restrict__ qta,
    us* __restrict__ ks, unsigned int* __restrict__ kta,
    us* __restrict__ vs, us* __restrict__ vtc)
{
  const int which = blockIdx.z;
  const us* X = (which == 0) ? Xqb : Xsb;
  const us* W = (which == 0) ? Wqb : (which == 1 ? Wkb : Wvb);
  const float* Bb = (which == 0) ? Bq : (which == 1 ? Bk : Bv);
  us* outs = (which == 0) ? qs : (which == 1 ? ks : vs);
  const float al2 = (2.0f / scale_p[0]) * 1.44269504088896f;
  const float oscale = (which == 0) ? al2 : 1.0f;

  const int lin = blockIdx.x;                    // 0..1023
  const int h   = (lin >> 3) & 7;
  const int m0  = (((lin >> 6) << 3) | (lin & 7)) * 64;
  const int n0  = h * 64;

  __shared__ alignas(16) us lX[2][64 * 64];
  __shared__ alignas(16) us lW[2][64 * 64];

  const int tid  = threadIdx.x;
  const int lane = tid & 63;
  const int wave = tid >> 6;
  const int arow = lane & 15;
  const int agrp = lane >> 4;
  const int rl   = lane >> 3;
  const int chx  = ((lane & 7) ^ rl) * 8;
  const int r0   = wave * 8 + rl;
  const int r1   = r0 + 32;

#define PSTAGE(buf, k0) do { \
    GLDS(X + (size_t)(m0 + r0) * INC + (k0) + chx, &lX[buf][wave * 512]); \
    GLDS(X + (size_t)(m0 + r1) * INC + (k0) + chx, &lX[buf][2048 + wave * 512]); \
    GLDS(W + (size_t)(n0 + r0) * INC + (k0) + chx, &lW[buf][wave * 512]); \
    GLDS(W + (size_t)(n0 + r1) * INC + (k0) + chx, &lW[buf][2048 + wave * 512]); \
  } while (0)

  f32x4 acc[4] = {};
  PSTAGE(0, 0);

  for (int kk = 0; kk < 8; ++kk) {
    const int cur = kk & 1;
    if (kk < 7) {
      PSTAGE(cur ^ 1, (kk + 1) * 64);
      asm volatile("s_waitcnt vmcnt(4)");
    } else {
      asm volatile("s_waitcnt vmcnt(0)");
    }
    __builtin_amdgcn_s_barrier();
#pragma unroll
    for (int kc = 0; kc < 2; ++kc) {
      short8 af = *(const short8*)&lX[cur][(wave * 16 + arow) * 64 + (((kc * 4 + agrp) ^ (arow & 7)) * 8)];
#pragma unroll
      for (int c = 0; c < 4; ++c) {
        short8 bf = *(const short8*)&lW[cur][(c * 16 + arow) * 64 + (((kc * 4 + agrp) ^ (arow & 7)) * 8)];
        acc[c] = __builtin_amdgcn_mfma_f32_16x16x32_bf16(af, bf, acc[c], 0, 0, 0);
      }
    }
    __builtin_amdgcn_s_barrier();
  }

  float bcol[4];
#pragma unroll
  for (int c = 0; c < 4; ++c) bcol[c] = Bb[n0 + c * 16 + arow];
#pragma unroll
  for (int r = 0; r < 4; ++r) {
    float s2 = 0.f;
#pragma unroll
    for (int c = 0; c < 4; ++c) {
      float v = acc[c][r] + bcol[c];
      acc[c][r] = v;
      s2 += v * v;
    }
    s2 += __shfl_xor(s2, 1); s2 += __shfl_xor(s2, 2);
    s2 += __shfl_xor(s2, 4); s2 += __shfl_xor(s2, 8);
    float tv = sqrtf(s2 + 1.0f);
    int gs = m0 + wave * 16 + agrp * 4 + r;
    int bi = gs >> 11, si = gs & (SEQ - 1);
    size_t rowbase = (size_t)(bi * NH + h) * SEQ + si;
    size_t obase = rowbase * 64;
#pragma unroll
    for (int c = 0; c < 4; ++c) outs[obase + c * 16 + arow] = f2b(oscale * acc[c][r]);
    if (arow == 0) {
      if (which == 0) {
        float st = al2 * tv;
        us qh = f2b(st);
        us ql = f2b(st - b2f(qh));
        qta[rowbase] = (unsigned int)qh | ((unsigned int)ql << 16);
      } else {
        us th = f2b(tv);
        us tl = f2b(tv - b2f(th));
        if (which == 1) {
          kta[rowbase] = (unsigned int)(us)(th ^ 0x8000)
                       | ((unsigned int)(us)(tl ^ 0x8000) << 16);
        } else {
          vtc[rowbase] = th;
          vtc[NROW + rowbase] = tl;
        }
      }
    }
  }
}

// ---------------------------------------------------------------------------
// Kernel 2: plain transpose of V space-part per (b,h): [S,64] -> [64,S].
// ---------------------------------------------------------------------------
__global__ __launch_bounds__(256) void transpose_v_kernel(
    const us* __restrict__ vs, us* __restrict__ vT)
{
  const int bh = blockIdx.y;
  const int s0 = blockIdx.x * 64;
  __shared__ us lT[64 * 80];
  const int tid = threadIdx.x;
#pragma unroll
  for (int u0 = 0; u0 < 2; ++u0) {
    int u = tid + u0 * 256;
    int row = u >> 3, ch = u & 7;
    short8 v = *(const short8*)&vs[((size_t)bh * SEQ + s0 + row) * 64 + ch * 8];
    *(short8*)&lT[row * 80 + ch * 8] = v;
  }
  __syncthreads();
#pragma unroll
  for (int u0 = 0; u0 < 2; ++u0) {
    int u = tid + u0 * 256;
    int o = u >> 3, sc = u & 7;
    short8 w;
#pragma unroll
    for (int j = 0; j < 8; ++j) w[j] = lT[(sc * 8 + j) * 80 + o];
    *(short8*)&vT[((size_t)bh * 64 + o) * SEQ + s0 + sc * 8] = w;
  }
}

// ---------------------------------------------------------------------------
// Kernel 3: causal flash attention, 8-wave blocks (512 thr), QBLK=128,
// KBLK=64. R7's per-wave tile body unchanged (16 q-rows/wave, lP roundtrip);
// staged K/V tile now feeds 8 waves -> LDS 43008 B -> 3 blocks/CU =
// 24 waves/CU (R7: 16). Grid 768 = 32 bh x 8 pairs {x,15-x} x 3-way split
// of the pair's exactly-36 k-tiles (12 tiles/block, balanced).
// vmcnt (per wave: 2 GLDS + 6 aug): steady vmcnt(2), last vmcnt(0).
// ---------------------------------------------------------------------------
__global__ __launch_bounds__(512) void attn_kernel(
    const us* __restrict__ qs, const unsigned int* __restrict__ qta,
    const us* __restrict__ ks, const unsigned int* __restrict__ kta,
    const us* __restrict__ vT, const us* __restrict__ vtc,
    float* __restrict__ part)
{
  // XCD-aware swizzle: the 24 blocks of one bh land on one XCD.
  const int f = blockIdx.x;              // 768 blocks
  const int xcd = f & 7, idx = f >> 3;   // idx in [0,96)
  const int bh = xcd * 4 + (idx / 24);
  const int inner = idx % 24;
  const int x = inner / 3;               // pair {x, 15-x}
  const int s = inner % 3;               // 3-way split slot
  const int n0 = 2 * x + 2;
  const int n1 = 32 - 2 * x;

  __shared__ alignas(16) us lK[2][64 * 64];
  __shared__ alignas(16) us lV[2][64 * 64];
  __shared__ alignas(16) us lP[8][16 * 40];

  const int tid  = threadIdx.x;
  const int lane = tid & 63;
  const int wave = tid >> 6;     // 0..7
  const int arow = lane & 15;
  const int agrp = lane >> 4;

  const size_t bhbase = (size_t)bh * SEQ;
  const us* kgp = ks + bhbase * 64;
  const us* vgp = vT + (size_t)bh * 64 * SEQ;
  const unsigned int* ktp = kta + bhbase;
  const us* vtp = vtc + (size_t)(arow & 1) * NROW + bhbase;

  const int rl   = lane >> 3;
  const int chx  = ((lane & 7) ^ rl) * 8;
  const int dsl0 = (agrp ^ (arow & 7)) * 8;
  const int dsl1 = ((4 + agrp) ^ (arow & 7)) * 8;
  us* myP = &lP[wave][0];
  const int pw0 = arow * 40 + agrp * 4;   // P b64 write (c=1: +16)
  const int prd = arow * 40 + agrp * 8;   // pf b128 read

#define ASTAGE(buf, t64) do { \
    const int kk = (t64) * 64; \
    GLDS(kgp + (size_t)(kk + wave * 8 + rl) * 64 + chx, &lK[buf][wave * 512]); \
    GLDS(vgp + (size_t)(wave * 8 + rl) * SEQ + kk + chx, &lV[buf][wave * 512]); \
  } while (0)

  short8 ones8, zero8 = {};
#pragma unroll
  for (int j = 0; j < 8; ++j) ones8[j] = (short)0x3F80;

  for (int seg = 0; seg < 2; ++seg) {
    const int qT = seg ? (15 - x) : x;
    int lo, hi;
    if (seg == 0) { lo = min(12 * s, n0);          hi = min(12 * s + 12, n0); }
    else          { lo = max(12 * s - n0, 0);      hi = min(12 * s + 12 - n0, n1); }
    const int nt = hi - lo;
    if (nt <= 0) continue;

    const int wq = qT * 128 + wave * 16 + arow;
    f32x4 acc[5] = {};

    // Q fragments + time terms (3 VMEM)
    const us* qp = qs + (bhbase + wq) * 64;
    short8 qf0 = *(const short8*)(qp + agrp * 8);
    short8 qf1 = *(const short8*)(qp + 32 + agrp * 8);
    unsigned int qw = qta[bhbase + wq];
    short8 qf2 = {};
    if (agrp == 0) {
      qf2[0] = (short)(qw & 0xFFFFu);
      qf2[1] = (short)(qw & 0xFFFFu);
      qf2[2] = (short)(qw >> 16);
    }

    // aug regs for first tile (4 + 2 = 6 VMEM)
    unsigned int ka[4];
    short8 va0, va1;
    {
      const int kk = lo * 64;
#pragma unroll
      for (int c = 0; c < 4; ++c) ka[c] = ktp[kk + c * 16 + arow];
      va0 = *(const short8*)(vtp + kk + agrp * 8);
      va1 = *(const short8*)(vtp + kk + 32 + agrp * 8);
    }
    SB();
    ASTAGE(0, lo);
    SB();

    for (int it = 0; it < nt; ++it) {
      const int t = lo + it;
      const int cur = it & 1;
      if (it < nt - 1) {
        ASTAGE(cur ^ 1, t + 1);
        SB();
        asm volatile("s_waitcnt vmcnt(2)");
      } else {
        SB();
        asm volatile("s_waitcnt vmcnt(0)");
      }
      SB();
      __builtin_amdgcn_s_barrier();

      const us* Kb = lK[cur];
      const us* Vb = lV[cur];

      // ---- S^T = K' Q'^T (augmented: includes -qt*kt hi/lo) ----
      f32x4 sS[4] = {};
      __builtin_amdgcn_s_setprio(1);
#pragma unroll
      for (int c = 0; c < 4; ++c) {
        short8 kf = *(const short8*)&Kb[(c * 16 + arow) * 64 + dsl0];
        sS[c] = __builtin_amdgcn_mfma_f32_16x16x32_bf16(kf, qf0, sS[c], 0, 0, 0);
      }
#pragma unroll
      for (int c = 0; c < 4; ++c) {
        short8 kf = *(const short8*)&Kb[(c * 16 + arow) * 64 + dsl1];
        sS[c] = __builtin_amdgcn_mfma_f32_16x16x32_bf16(kf, qf1, sS[c], 0, 0, 0);
      }
#pragma unroll
      for (int c = 0; c < 4; ++c) {
        short8 kf2 = {};
        if (agrp == 0) {
          unsigned int w0 = ka[c];
          kf2[0] = (short)(w0 & 0xFFFFu);
          kf2[1] = (short)(w0 >> 16);
          kf2[2] = (short)(w0 & 0xFFFFu);
        }
        sS[c] = __builtin_amdgcn_mfma_f32_16x16x32_bf16(kf2, qf2, sS[c], 0, 0, 0);
      }
      __builtin_amdgcn_s_setprio(0);

      // ---- P = exp2(logit) (Q pre-scaled); causal mask -> exact 0 ----
#pragma unroll
      for (int c = 0; c < 4; ++c)
#pragma unroll
        for (int r = 0; r < 4; ++r)
          sS[c][r] = exp2f(sS[c][r]);
      if (t >= 2 * qT) {     // the two diagonal-straddling k-tiles
        const int kb = t * 64;
#pragma unroll
        for (int c = 0; c < 4; ++c)
#pragma unroll
          for (int r = 0; r < 4; ++r)
            if (kb + c * 16 + agrp * 4 + r > wq) sS[c][r] = 0.f;
      }

      // ---- PV: 2 phases over kc, wave-private 1.25KB P tile reused ----
      {
        uint2v w;
        w[0] = pk2(sS[0][0], sS[0][1]); w[1] = pk2(sS[0][2], sS[0][3]);
        *(uint2v*)&myP[pw0] = w;
        w[0] = pk2(sS[1][0], sS[1][1]); w[1] = pk2(sS[1][2], sS[1][3]);
        *(uint2v*)&myP[pw0 + 16] = w;
        short8 pf = *(const short8*)&myP[prd];
        __builtin_amdgcn_s_setprio(1);
#pragma unroll
        for (int dc = 0; dc < 4; ++dc) {
          short8 vf = *(const short8*)&Vb[(dc * 16 + arow) * 64 + dsl0];
          acc[dc] = __builtin_amdgcn_mfma_f32_16x16x32_bf16(pf, vf, acc[dc], 0, 0, 0);
        }
        short8 vf4 = (arow < 2) ? va0 : ((arow == 2) ? ones8 : zero8);
        acc[4] = __builtin_amdgcn_mfma_f32_16x16x32_bf16(pf, vf4, acc[4], 0, 0, 0);
        __builtin_amdgcn_s_setprio(0);
      }
      {
        uint2v w;
        w[0] = pk2(sS[2][0], sS[2][1]); w[1] = pk2(sS[2][2], sS[2][3]);
        *(uint2v*)&myP[pw0] = w;
        w[0] = pk2(sS[3][0], sS[3][1]); w[1] = pk2(sS[3][2], sS[3][3]);
        *(uint2v*)&myP[pw0 + 16] = w;
        short8 pf = *(const short8*)&myP[prd];
        __builtin_amdgcn_s_setprio(1);
#pragma unroll
        for (int dc = 0; dc < 4; ++dc) {
          short8 vf = *(const short8*)&Vb[(dc * 16 + arow) * 64 + dsl1];
          acc[dc] = __builtin_amdgcn_mfma_f32_16x16x32_bf16(pf, vf, acc[dc], 0, 0, 0);
        }
        short8 vf4 = (arow < 2) ? va1 : ((arow == 2) ? ones8 : zero8);
        acc[4] = __builtin_amdgcn_mfma_f32_16x16x32_bf16(pf, vf4, acc[4], 0, 0, 0);
        __builtin_amdgcn_s_setprio(0);
      }

      // aug prefetch for next tile (in flight across the barrier)
      SB();
      if (it + 1 < nt) {
        const int kk = (t + 1) * 64;
#pragma unroll
        for (int c = 0; c < 4; ++c) ka[c] = ktp[kk + c * 16 + arow];
        va0 = *(const short8*)(vtp + kk + agrp * 8);
        va1 = *(const short8*)(vtp + kk + 32 + agrp * 8);
      }
      SB();
      __builtin_amdgcn_s_barrier();   // reads done: safe to overwrite other buf
    }

    // ---- epilogue: write un-normalized partial slot (qT, s) ----
    const size_t pb = ((size_t)(bh * 16 + qT) * 3 + s) * 128;
#pragma unroll
    for (int r = 0; r < 4; ++r) {
      float t0 = __shfl(acc[4][r], (agrp << 4) | 0);
      float t1 = __shfl(acc[4][r], (agrp << 4) | 1);
      float ls = __shfl(acc[4][r], (agrp << 4) | 2);
      size_t rp = (pb + wave * 16 + agrp * 4 + r) * 68;
#pragma unroll
      for (int dc = 0; dc < 4; ++dc)
        part[rp + dc * 16 + arow] = acc[dc][r];
      if (arow == 0) {
        part[rp + 64] = t0 + t1;
        part[rp + 65] = ls;
      }
    }
  }
}

// ---------------------------------------------------------------------------
// Kernel 4: merge split-k partials (exact sums), mean over heads, Lorentz
// normalization. Slot validity per qT (matches attn's clamp arithmetic):
// v0: qT<=7 || qT>=11;  v1: qT>=6;  v2: qT>=8. Untouched slots never read.
// ---------------------------------------------------------------------------
__global__ __launch_bounds__(256) void finalize_kernel(
    const float* __restrict__ part, float* __restrict__ out)
{
  const int tid  = threadIdx.x;
  const int lane = tid & 63;
  const int gw = blockIdx.x * 4 + (tid >> 6);
  const int b = gw >> 11, si = gw & (SEQ - 1);
  const int qT = si >> 7, row = si & 127;

  const bool v0 = (qT <= 7) || (qT >= 11);
  const bool v1 = (qT >= 6);
  const bool v2 = (qT >= 8);

  float vsum = 0.f, tsum = 0.f;
#pragma unroll
  for (int h = 0; h < NH; ++h) {
    const size_t tb = ((size_t)(b * NH + h) * 16 + qT) * 3;
    float Ah = 0.f, Th = 0.f, Lh = 0.f;
    if (v0) {
      size_t rb = ((tb + 0) * 128 + row) * 68;
      Ah += part[rb + lane]; Th += part[rb + 64]; Lh += part[rb + 65];
    }
    if (v1) {
      size_t rb = ((tb + 1) * 128 + row) * 68;
      Ah += part[rb + lane]; Th += part[rb + 64]; Lh += part[rb + 65];
    }
    if (v2) {
      size_t rb = ((tb + 2) * 128 + row) * 68;
      Ah += part[rb + lane]; Th += part[rb + 64]; Lh += part[rb + 65];
    }
    float inv = 1.0f / Lh;
    vsum = fmaf(Ah, inv, vsum);
    tsum = fmaf(Th, inv, tsum);
  }
  float ave  = vsum * 0.125f;
  float tave = tsum * 0.125f;
  float contrib = ave * ave;
  if (lane == 0) contrib -= tave * tave;
  contrib += __shfl_xor(contrib, 1);
  contrib += __shfl_xor(contrib, 2);
  contrib += __shfl_xor(contrib, 4);
  contrib += __shfl_xor(contrib, 8);
  contrib += __shfl_xor(contrib, 16);
  contrib += __shfl_xor(contrib, 32);
  float denom = sqrtf(fmaxf(fabsf(contrib), 1e-8f));
  size_t ob = ((size_t)b * SEQ + si) * (size_t)DD;
  out[ob + 1 + lane] = ave / denom;
  if (lane == 0) out[ob] = tave / denom;
}

// ---------------------------------------------------------------------------
extern "C" void kernel_launch(void* const* d_in, const int* in_sizes, int n_in,
                              void* d_out, int out_size, void* d_ws, size_t ws_size,
                              hipStream_t stream) {
  const float* Xq  = (const float*)d_in[0];
  const float* Xs  = (const float*)d_in[1];
  const float* Wq  = (const float*)d_in[2];
  const float* Bq  = (const float*)d_in[3];
  const float* Wk  = (const float*)d_in[4];
  const float* Bk  = (const float*)d_in[5];
  const float* Wv  = (const float*)d_in[6];
  const float* Bv  = (const float*)d_in[7];
  const float* scale = (const float*)d_in[8];
  float* out = (float*)d_out;

  char* p = (char*)d_ws;

  // Region 0 (53.5 MB): partials, overlapped with bf16 X/W copies and vs
  // (all consumed before attn writes part).
  float* part = (float*)p;
  us* Xqb   = (us*)p;
  us* Xsb   = (us*)(p + 16777216);
  us* Wqb16 = (us*)(p + 33554432);
  us* Wkb16 = (us*)(p + 34078720);
  us* Wvb16 = (us*)(p + 34603008);
  us* vsb   = (us*)(p + 35651584);                 // +8.4MB ends 44.0MB < 53.5MB
  p += (size_t)32 * 16 * 3 * 128 * 68 * 4;         // 53,477,376
  us* qsb = (us*)p; p += (size_t)NROW * 64 * 2;
  us* ksb = (us*)p; p += (size_t)NROW * 64 * 2;
  us* vTb = (us*)p; p += (size_t)NROW * 64 * 2;
  unsigned int* qtaw = (unsigned int*)p; p += (size_t)NROW * 4;
  unsigned int* ktaw = (unsigned int*)p; p += (size_t)NROW * 4;
  us* vtcw = (us*)p; p += (size_t)NROW * 2 * 2;

  tobf16_kernel<<<dim3(1024, 5), 256, 0, stream>>>(
      Xq, Xs, Wq, Wk, Wv, Xqb, Xsb, Wqb16, Wkb16, Wvb16);
  proj_kernel<<<dim3(1024, 1, 3), 256, 0, stream>>>(
      Xqb, Xsb, Wqb16, Wkb16, Wvb16, Bq, Bk, Bv, scale,
      qsb, qtaw, ksb, ktaw, vsb, vtcw);
  transpose_v_kernel<<<dim3(SEQ / 64, BATCH * NH), 256, 0, stream>>>(vsb, vTb);
  attn_kernel<<<dim3(768), 512, 0, stream>>>(
      qsb, qtaw, ksb, ktaw, vTb, vtcw, part);
  finalize_kernel<<<(BATCH * SEQ) / 4, 256, 0, stream>>>(part, out);
}

// Round 13
// 96.221 us; speedup vs baseline: 1.0883x; 1.0438x over previous
//
#include <hip/hip_runtime.h>

// Problem constants
#define BATCH 4
#define SEQ   2048
#define INC   512
#define NH    8
#define OUTC  64      // space dim; head dim = 65
#define DD    65
#define NROW  (BATCH * NH * SEQ)   // 65536
#define PSTRIDE 72    // partial row stride in us units (144 B)

typedef float f32x4 __attribute__((ext_vector_type(4)));
typedef short short8 __attribute__((ext_vector_type(8)));
typedef short short4v __attribute__((ext_vector_type(4)));
typedef unsigned int uint2v __attribute__((ext_vector_type(2)));
typedef unsigned short us;

static __device__ __forceinline__ us f2b(float f) {
  unsigned int u = __float_as_uint(f);
  u = (u + 0x7FFFu + ((u >> 16) & 1u)) >> 16;   // RNE f32->bf16
  return (us)u;
}
static __device__ __forceinline__ float b2f(us h) {
  return __uint_as_float(((unsigned int)h) << 16);
}
static __device__ __forceinline__ unsigned int pk2(float lo, float hi) {
  unsigned int r;
  asm("v_cvt_pk_bf16_f32 %0, %1, %2" : "=v"(r) : "v"(lo), "v"(hi));
  return r;
}

#define GLDS(g, l) __builtin_amdgcn_global_load_lds( \
    (const __attribute__((address_space(1))) void*)(g), \
    (__attribute__((address_space(3))) void*)(l), 16, 0, 0)
#define SB() __builtin_amdgcn_sched_barrier(0)

// ---------------------------------------------------------------------------
// Kernel 0: f32 -> bf16 conversion for X (both) and W (all three).
// ---------------------------------------------------------------------------
__global__ __launch_bounds__(256) void tobf16_kernel(
    const float* __restrict__ Xq, const float* __restrict__ Xs,
    const float* __restrict__ Wq, const float* __restrict__ Wk,
    const float* __restrict__ Wv,
    us* __restrict__ dXq, us* __restrict__ dXs,
    us* __restrict__ dWq, us* __restrict__ dWk, us* __restrict__ dWv)
{
  const int which = blockIdx.y;
  const float* src;
  us* dst;
  int n;
  switch (which) {
    case 0: src = Xq; dst = dXq; n = BATCH * SEQ * INC; break;
    case 1: src = Xs; dst = dXs; n = BATCH * SEQ * INC; break;
    case 2: src = Wq; dst = dWq; n = NH * OUTC * INC; break;
    case 3: src = Wk; dst = dWk; n = NH * OUTC * INC; break;
    default: src = Wv; dst = dWv; n = NH * OUTC * INC; break;
  }
  for (long i = (long)blockIdx.x * 256 + threadIdx.x; i * 4 < n;
       i += (long)gridDim.x * 256) {
    f32x4 v = *(const f32x4*)(src + i * 4);
    short4v o;
    o[0] = (short)f2b(v[0]); o[1] = (short)f2b(v[1]);
    o[2] = (short)f2b(v[2]); o[3] = (short)f2b(v[3]);
    *(short4v*)(dst + i * 4) = o;
  }
}

// ---------------------------------------------------------------------------
// Kernel 1: per-head projections, GLDS double-buffered.
//   Q: space pre-scaled by al2; qta u32 = (qh|ql<<16) of al2*t.
//   K: kta u32 = (-kh)|(-kl)<<16.
//   V: TRANSPOSED in the epilogue via LDS -> writes vT [B,H,64,S] directly
//      (transpose kernel deleted); vtc bf16 planes {hi,lo} of t.
// ---------------------------------------------------------------------------
__global__ __launch_bounds__(256) void proj_kernel(
    const us* __restrict__ Xqb, const us* __restrict__ Xsb,
    const us* __restrict__ Wqb, const us* __restrict__ Wkb, const us* __restrict__ Wvb,
    const float* __restrict__ Bq, const float* __restrict__ Bk, const float* __restrict__ Bv,
    const float* __restrict__ scale_p,
    us* __restrict__ qs, unsigned int* __restrict__ qta,
    us* __restrict__ ks, unsigned int* __restrict__ kta,
    us* __restrict__ vT, us* __restrict__ vtc)
{
  const int which = blockIdx.z;
  const us* X = (which == 0) ? Xqb : Xsb;
  const us* W = (which == 0) ? Wqb : (which == 1 ? Wkb : Wvb);
  const float* Bb = (which == 0) ? Bq : (which == 1 ? Bk : Bv);
  const float al2 = (2.0f / scale_p[0]) * 1.44269504088896f;
  const float oscale = (which == 0) ? al2 : 1.0f;

  const int lin = blockIdx.x;                    // 0..1023
  const int h   = (lin >> 3) & 7;
  const int m0  = (((lin >> 6) << 3) | (lin & 7)) * 64;
  const int n0  = h * 64;

  __shared__ alignas(16) us lXf[2 * 64 * 64];
  __shared__ alignas(16) us lWf[2 * 64 * 64];

  const int tid  = threadIdx.x;
  const int lane = tid & 63;
  const int wave = tid >> 6;
  const int arow = lane & 15;
  const int agrp = lane >> 4;
  const int rl   = lane >> 3;
  const int chx  = ((lane & 7) ^ rl) * 8;
  const int r0   = wave * 8 + rl;
  const int r1   = r0 + 32;

#define PSTAGE(buf, k0) do { \
    GLDS(X + (size_t)(m0 + r0) * INC + (k0) + chx, &lXf[(buf) * 4096 + wave * 512]); \
    GLDS(X + (size_t)(m0 + r1) * INC + (k0) + chx, &lXf[(buf) * 4096 + 2048 + wave * 512]); \
    GLDS(W + (size_t)(n0 + r0) * INC + (k0) + chx, &lWf[(buf) * 4096 + wave * 512]); \
    GLDS(W + (size_t)(n0 + r1) * INC + (k0) + chx, &lWf[(buf) * 4096 + 2048 + wave * 512]); \
  } while (0)

  f32x4 acc[4] = {};
  PSTAGE(0, 0);

  for (int kk = 0; kk < 8; ++kk) {
    const int cur = kk & 1;
    if (kk < 7) {
      PSTAGE(cur ^ 1, (kk + 1) * 64);
      asm volatile("s_waitcnt vmcnt(4)");
    } else {
      asm volatile("s_waitcnt vmcnt(0)");
    }
    __builtin_amdgcn_s_barrier();
#pragma unroll
    for (int kc = 0; kc < 2; ++kc) {
      short8 af = *(const short8*)&lXf[cur * 4096 + (wave * 16 + arow) * 64 + (((kc * 4 + agrp) ^ (arow & 7)) * 8)];
#pragma unroll
      for (int c = 0; c < 4; ++c) {
        short8 bf = *(const short8*)&lWf[cur * 4096 + (c * 16 + arow) * 64 + (((kc * 4 + agrp) ^ (arow & 7)) * 8)];
        acc[c] = __builtin_amdgcn_mfma_f32_16x16x32_bf16(af, bf, acc[c], 0, 0, 0);
      }
    }
    __builtin_amdgcn_s_barrier();
  }
  // After the final barrier all waves are done reading lXf/lWf -> reusable.

  float bcol[4];
#pragma unroll
  for (int c = 0; c < 4; ++c) bcol[c] = Bb[n0 + c * 16 + arow];

  us* lT = &lXf[0];   // 64 x 72 us transpose tile (V path only)

#pragma unroll
  for (int r = 0; r < 4; ++r) {
    float s2 = 0.f;
#pragma unroll
    for (int c = 0; c < 4; ++c) {
      float v = acc[c][r] + bcol[c];
      acc[c][r] = v;
      s2 += v * v;
    }
    s2 += __shfl_xor(s2, 1); s2 += __shfl_xor(s2, 2);
    s2 += __shfl_xor(s2, 4); s2 += __shfl_xor(s2, 8);
    float tv = sqrtf(s2 + 1.0f);
    int gs = m0 + wave * 16 + agrp * 4 + r;
    int bi = gs >> 11, si = gs & (SEQ - 1);
    size_t rowbase = (size_t)(bi * NH + h) * SEQ + si;
    if (which == 2) {
      // stage bf16 V rows into LDS for the in-kernel transpose
      int lrow = wave * 16 + agrp * 4 + r;
#pragma unroll
      for (int c = 0; c < 4; ++c)
        lT[lrow * PSTRIDE + c * 16 + arow] = f2b(acc[c][r]);
      if (arow == 0) {
        us th = f2b(tv);
        us tl = f2b(tv - b2f(th));
        vtc[rowbase] = th;
        vtc[NROW + rowbase] = tl;
      }
    } else {
      us* outs = (which == 0) ? qs : ks;
      size_t obase = rowbase * 64;
#pragma unroll
      for (int c = 0; c < 4; ++c) outs[obase + c * 16 + arow] = f2b(oscale * acc[c][r]);
      if (arow == 0) {
        if (which == 0) {
          float st = al2 * tv;
          us qh = f2b(st);
          us ql = f2b(st - b2f(qh));
          qta[rowbase] = (unsigned int)qh | ((unsigned int)ql << 16);
        } else {
          kta[rowbase] = (unsigned int)(us)(f2b(tv) ^ 0x8000)
                       | ((unsigned int)(us)(f2b(tv - b2f(f2b(tv))) ^ 0x8000) << 16);
        }
      }
    }
  }

  if (which == 2) {
    __syncthreads();
    const int bi = m0 >> 11, si0 = m0 & (SEQ - 1);
    us* vbase = vT + ((size_t)(bi * NH + h) * 64) * SEQ + si0;
#pragma unroll
    for (int u0 = 0; u0 < 2; ++u0) {
      int u = tid + u0 * 256;
      int o = u >> 3, jc = u & 7;
      short8 w;
#pragma unroll
      for (int j = 0; j < 8; ++j) w[j] = (short)lT[(jc * 8 + j) * PSTRIDE + o];
      *(short8*)(vbase + (size_t)o * SEQ + jc * 8) = w;
    }
  }
}

// ---------------------------------------------------------------------------
// Kernel 3: causal flash attention (R12 structure, unchanged): 8-wave blocks
// (512 thr), QBLK=128, KBLK=64, grid 768 = 32 bh x 8 pairs {x,15-x} x 3-way
// split of the pair's 36 k-tiles. Partials now 144 B/row: 64 bf16 space
// sums + t,l f32.
// ---------------------------------------------------------------------------
__global__ __launch_bounds__(512) void attn_kernel(
    const us* __restrict__ qs, const unsigned int* __restrict__ qta,
    const us* __restrict__ ks, const unsigned int* __restrict__ kta,
    const us* __restrict__ vT, const us* __restrict__ vtc,
    us* __restrict__ part)
{
  // XCD-aware swizzle: the 24 blocks of one bh land on one XCD.
  const int f = blockIdx.x;              // 768 blocks
  const int xcd = f & 7, idx = f >> 3;   // idx in [0,96)
  const int bh = xcd * 4 + (idx / 24);
  const int inner = idx % 24;
  const int x = inner / 3;               // pair {x, 15-x}
  const int s = inner % 3;               // 3-way split slot
  const int n0 = 2 * x + 2;
  const int n1 = 32 - 2 * x;

  __shared__ alignas(16) us lK[2][64 * 64];
  __shared__ alignas(16) us lV[2][64 * 64];
  __shared__ alignas(16) us lP[8][16 * 40];

  const int tid  = threadIdx.x;
  const int lane = tid & 63;
  const int wave = tid >> 6;     // 0..7
  const int arow = lane & 15;
  const int agrp = lane >> 4;

  const size_t bhbase = (size_t)bh * SEQ;
  const us* kgp = ks + bhbase * 64;
  const us* vgp = vT + (size_t)bh * 64 * SEQ;
  const unsigned int* ktp = kta + bhbase;
  const us* vtp = vtc + (size_t)(arow & 1) * NROW + bhbase;

  const int rl   = lane >> 3;
  const int chx  = ((lane & 7) ^ rl) * 8;
  const int dsl0 = (agrp ^ (arow & 7)) * 8;
  const int dsl1 = ((4 + agrp) ^ (arow & 7)) * 8;
  us* myP = &lP[wave][0];
  const int pw0 = arow * 40 + agrp * 4;   // P b64 write (c=1: +16)
  const int prd = arow * 40 + agrp * 8;   // pf b128 read

#define ASTAGE(buf, t64) do { \
    const int kk = (t64) * 64; \
    GLDS(kgp + (size_t)(kk + wave * 8 + rl) * 64 + chx, &lK[buf][wave * 512]); \
    GLDS(vgp + (size_t)(wave * 8 + rl) * SEQ + kk + chx, &lV[buf][wave * 512]); \
  } while (0)

  short8 ones8, zero8 = {};
#pragma unroll
  for (int j = 0; j < 8; ++j) ones8[j] = (short)0x3F80;

  for (int seg = 0; seg < 2; ++seg) {
    const int qT = seg ? (15 - x) : x;
    int lo, hi;
    if (seg == 0) { lo = min(12 * s, n0);          hi = min(12 * s + 12, n0); }
    else          { lo = max(12 * s - n0, 0);      hi = min(12 * s + 12 - n0, n1); }
    const int nt = hi - lo;
    if (nt <= 0) continue;

    const int wq = qT * 128 + wave * 16 + arow;
    f32x4 acc[5] = {};

    // Q fragments + time terms (3 VMEM)
    const us* qp = qs + (bhbase + wq) * 64;
    short8 qf0 = *(const short8*)(qp + agrp * 8);
    short8 qf1 = *(const short8*)(qp + 32 + agrp * 8);
    unsigned int qw = qta[bhbase + wq];
    short8 qf2 = {};
    if (agrp == 0) {
      qf2[0] = (short)(qw & 0xFFFFu);
      qf2[1] = (short)(qw & 0xFFFFu);
      qf2[2] = (short)(qw >> 16);
    }

    // aug regs for first tile (4 + 2 = 6 VMEM)
    unsigned int ka[4];
    short8 va0, va1;
    {
      const int kk = lo * 64;
#pragma unroll
      for (int c = 0; c < 4; ++c) ka[c] = ktp[kk + c * 16 + arow];
      va0 = *(const short8*)(vtp + kk + agrp * 8);
      va1 = *(const short8*)(vtp + kk + 32 + agrp * 8);
    }
    SB();
    ASTAGE(0, lo);
    SB();

    for (int it = 0; it < nt; ++it) {
      const int t = lo + it;
      const int cur = it & 1;
      if (it < nt - 1) {
        ASTAGE(cur ^ 1, t + 1);
        SB();
        asm volatile("s_waitcnt vmcnt(2)");
      } else {
        SB();
        asm volatile("s_waitcnt vmcnt(0)");
      }
      SB();
      __builtin_amdgcn_s_barrier();

      const us* Kb = lK[cur];
      const us* Vb = lV[cur];

      // ---- S^T = K' Q'^T (augmented: includes -qt*kt hi/lo) ----
      f32x4 sS[4] = {};
      __builtin_amdgcn_s_setprio(1);
#pragma unroll
      for (int c = 0; c < 4; ++c) {
        short8 kf = *(const short8*)&Kb[(c * 16 + arow) * 64 + dsl0];
        sS[c] = __builtin_amdgcn_mfma_f32_16x16x32_bf16(kf, qf0, sS[c], 0, 0, 0);
      }
#pragma unroll
      for (int c = 0; c < 4; ++c) {
        short8 kf = *(const short8*)&Kb[(c * 16 + arow) * 64 + dsl1];
        sS[c] = __builtin_amdgcn_mfma_f32_16x16x32_bf16(kf, qf1, sS[c], 0, 0, 0);
      }
#pragma unroll
      for (int c = 0; c < 4; ++c) {
        short8 kf2 = {};
        if (agrp == 0) {
          unsigned int w0 = ka[c];
          kf2[0] = (short)(w0 & 0xFFFFu);
          kf2[1] = (short)(w0 >> 16);
          kf2[2] = (short)(w0 & 0xFFFFu);
        }
        sS[c] = __builtin_amdgcn_mfma_f32_16x16x32_bf16(kf2, qf2, sS[c], 0, 0, 0);
      }
      __builtin_amdgcn_s_setprio(0);

      // ---- P = exp2(logit) (Q pre-scaled); causal mask -> exact 0 ----
#pragma unroll
      for (int c = 0; c < 4; ++c)
#pragma unroll
        for (int r = 0; r < 4; ++r)
          sS[c][r] = exp2f(sS[c][r]);
      if (t >= 2 * qT) {     // the two diagonal-straddling k-tiles
        const int kb = t * 64;
#pragma unroll
        for (int c = 0; c < 4; ++c)
#pragma unroll
          for (int r = 0; r < 4; ++r)
            if (kb + c * 16 + agrp * 4 + r > wq) sS[c][r] = 0.f;
      }

      // ---- PV: 2 phases over kc, wave-private 1.25KB P tile reused ----
      {
        uint2v w;
        w[0] = pk2(sS[0][0], sS[0][1]); w[1] = pk2(sS[0][2], sS[0][3]);
        *(uint2v*)&myP[pw0] = w;
        w[0] = pk2(sS[1][0], sS[1][1]); w[1] = pk2(sS[1][2], sS[1][3]);
        *(uint2v*)&myP[pw0 + 16] = w;
        short8 pf = *(const short8*)&myP[prd];
        __builtin_amdgcn_s_setprio(1);
#pragma unroll
        for (int dc = 0; dc < 4; ++dc) {
          short8 vf = *(const short8*)&Vb[(dc * 16 + arow) * 64 + dsl0];
          acc[dc] = __builtin_amdgcn_mfma_f32_16x16x32_bf16(pf, vf, acc[dc], 0, 0, 0);
        }
        short8 vf4 = (arow < 2) ? va0 : ((arow == 2) ? ones8 : zero8);
        acc[4] = __builtin_amdgcn_mfma_f32_16x16x32_bf16(pf, vf4, acc[4], 0, 0, 0);
        __builtin_amdgcn_s_setprio(0);
      }
      {
        uint2v w;
        w[0] = pk2(sS[2][0], sS[2][1]); w[1] = pk2(sS[2][2], sS[2][3]);
        *(uint2v*)&myP[pw0] = w;
        w[0] = pk2(sS[3][0], sS[3][1]); w[1] = pk2(sS[3][2], sS[3][3]);
        *(uint2v*)&myP[pw0 + 16] = w;
        short8 pf = *(const short8*)&myP[prd];
        __builtin_amdgcn_s_setprio(1);
#pragma unroll
        for (int dc = 0; dc < 4; ++dc) {
          short8 vf = *(const short8*)&Vb[(dc * 16 + arow) * 64 + dsl1];
          acc[dc] = __builtin_amdgcn_mfma_f32_16x16x32_bf16(pf, vf, acc[dc], 0, 0, 0);
        }
        short8 vf4 = (arow < 2) ? va1 : ((arow == 2) ? ones8 : zero8);
        acc[4] = __builtin_amdgcn_mfma_f32_16x16x32_bf16(pf, vf4, acc[4], 0, 0, 0);
        __builtin_amdgcn_s_setprio(0);
      }

      // aug prefetch for next tile (in flight across the barrier)
      SB();
      if (it + 1 < nt) {
        const int kk = (t + 1) * 64;
#pragma unroll
        for (int c = 0; c < 4; ++c) ka[c] = ktp[kk + c * 16 + arow];
        va0 = *(const short8*)(vtp + kk + agrp * 8);
        va1 = *(const short8*)(vtp + kk + 32 + agrp * 8);
      }
      SB();
      __builtin_amdgcn_s_barrier();   // reads done: safe to overwrite other buf
    }

    // ---- epilogue: partial slot (qT, s): 64 bf16 + t,l f32 per row ----
    const size_t pb = ((size_t)(bh * 16 + qT) * 3 + s) * 128;
#pragma unroll
    for (int r = 0; r < 4; ++r) {
      float t0 = __shfl(acc[4][r], (agrp << 4) | 0);
      float t1 = __shfl(acc[4][r], (agrp << 4) | 1);
      float ls = __shfl(acc[4][r], (agrp << 4) | 2);
      size_t rp = (pb + wave * 16 + agrp * 4 + r) * PSTRIDE;
#pragma unroll
      for (int dc = 0; dc < 4; ++dc)
        part[rp + dc * 16 + arow] = f2b(acc[dc][r]);
      if (arow == 0) {
        float* fp = (float*)(part + rp + 64);
        fp[0] = t0 + t1;
        fp[1] = ls;
      }
    }
  }
}

// ---------------------------------------------------------------------------
// Kernel 4: merge split-k partials (exact sums), mean over heads, Lorentz
// normalization. Slot validity per qT: v0: qT<=7||qT>=11; v1: qT>=6;
// v2: qT>=8 (matches attn's clamp arithmetic). Partials: bf16 A + f32 t,l.
// ---------------------------------------------------------------------------
__global__ __launch_bounds__(256) void finalize_kernel(
    const us* __restrict__ part, float* __restrict__ out)
{
  const int tid  = threadIdx.x;
  const int lane = tid & 63;
  const int gw = blockIdx.x * 4 + (tid >> 6);
  const int b = gw >> 11, si = gw & (SEQ - 1);
  const int qT = si >> 7, row = si & 127;

  const bool v0 = (qT <= 7) || (qT >= 11);
  const bool v1 = (qT >= 6);
  const bool v2 = (qT >= 8);

  float vsum = 0.f, tsum = 0.f;
#pragma unroll
  for (int h = 0; h < NH; ++h) {
    const size_t tb = ((size_t)(b * NH + h) * 16 + qT) * 3;
    float Ah = 0.f, Th = 0.f, Lh = 0.f;
    if (v0) {
      size_t rb = ((tb + 0) * 128 + row) * PSTRIDE;
      Ah += b2f(part[rb + lane]);
      const float* fp = (const float*)(part + rb + 64);
      Th += fp[0]; Lh += fp[1];
    }
    if (v1) {
      size_t rb = ((tb + 1) * 128 + row) * PSTRIDE;
      Ah += b2f(part[rb + lane]);
      const float* fp = (const float*)(part + rb + 64);
      Th += fp[0]; Lh += fp[1];
    }
    if (v2) {
      size_t rb = ((tb + 2) * 128 + row) * PSTRIDE;
      Ah += b2f(part[rb + lane]);
      const float* fp = (const float*)(part + rb + 64);
      Th += fp[0]; Lh += fp[1];
    }
    float inv = 1.0f / Lh;
    vsum = fmaf(Ah, inv, vsum);
    tsum = fmaf(Th, inv, tsum);
  }
  float ave  = vsum * 0.125f;
  float tave = tsum * 0.125f;
  float contrib = ave * ave;
  if (lane == 0) contrib -= tave * tave;
  contrib += __shfl_xor(contrib, 1);
  contrib += __shfl_xor(contrib, 2);
  contrib += __shfl_xor(contrib, 4);
  contrib += __shfl_xor(contrib, 8);
  contrib += __shfl_xor(contrib, 16);
  contrib += __shfl_xor(contrib, 32);
  float denom = sqrtf(fmaxf(fabsf(contrib), 1e-8f));
  size_t ob = ((size_t)b * SEQ + si) * (size_t)DD;
  out[ob + 1 + lane] = ave / denom;
  if (lane == 0) out[ob] = tave / denom;
}

// ---------------------------------------------------------------------------
extern "C" void kernel_launch(void* const* d_in, const int* in_sizes, int n_in,
                              void* d_out, int out_size, void* d_ws, size_t ws_size,
                              hipStream_t stream) {
  const float* Xq  = (const float*)d_in[0];
  const float* Xs  = (const float*)d_in[1];
  const float* Wq  = (const float*)d_in[2];
  const float* Bq  = (const float*)d_in[3];
  const float* Wk  = (const float*)d_in[4];
  const float* Bk  = (const float*)d_in[5];
  const float* Wv  = (const float*)d_in[6];
  const float* Bv  = (const float*)d_in[7];
  const float* scale = (const float*)d_in[8];
  float* out = (float*)d_out;

  char* p = (char*)d_ws;

  // Region 0 (35.7 MB): partials (28.3 MB) overlapped with bf16 X and W
  // copies (proj consumes Xb/Wb before attn writes part).
  us* partw = (us*)p;
  us* Xqb   = (us*)p;
  us* Xsb   = (us*)(p + 16777216);
  us* Wqb16 = (us*)(p + 33554432);
  us* Wkb16 = (us*)(p + 34078720);
  us* Wvb16 = (us*)(p + 34603008);
  p += 35651584;
  us* qsb = (us*)p; p += (size_t)NROW * 64 * 2;
  us* ksb = (us*)p; p += (size_t)NROW * 64 * 2;
  us* vTb = (us*)p; p += (size_t)NROW * 64 * 2;
  unsigned int* qtaw = (unsigned int*)p; p += (size_t)NROW * 4;
  unsigned int* ktaw = (unsigned int*)p; p += (size_t)NROW * 4;
  us* vtcw = (us*)p; p += (size_t)NROW * 2 * 2;

  tobf16_kernel<<<dim3(1024, 5), 256, 0, stream>>>(
      Xq, Xs, Wq, Wk, Wv, Xqb, Xsb, Wqb16, Wkb16, Wvb16);
  proj_kernel<<<dim3(1024, 1, 3), 256, 0, stream>>>(
      Xqb, Xsb, Wqb16, Wkb16, Wvb16, Bq, Bk, Bv, scale,
      qsb, qtaw, ksb, ktaw, vTb, vtcw);
  attn_kernel<<<dim3(768), 512, 0, stream>>>(
      qsb, qtaw, ksb, ktaw, vTb, vtcw, partw);
  finalize_kernel<<<(BATCH * SEQ) / 4, 256, 0, stream>>>(partw, out);
}